// Round 1
// baseline (497.689 us; speedup 1.0000x reference)
//
#include <hip/hip_runtime.h>

typedef __attribute__((ext_vector_type(8))) short bf16x8;
typedef __attribute__((ext_vector_type(4))) float f32x4;
typedef __attribute__((ext_vector_type(4))) unsigned short u16x4;
typedef unsigned short ushort_t;
typedef unsigned int uint32;

constexpr int B_ = 2, S_ = 2048, D_ = 1024, H_ = 16, DH_ = 64;
constexpr int M_TOK = B_ * S_;    // 4096
constexpr int N_QKV = 3 * D_;     // 3072

#define DEV __device__ __forceinline__

DEV ushort_t f2bf(float f) {
  uint32 u = __builtin_bit_cast(uint32, f);
  u += 0x7fffu + ((u >> 16) & 1u);
  return (ushort_t)(u >> 16);
}

DEV void gll16(const void* g, void* l) {
  __builtin_amdgcn_global_load_lds(
      (const __attribute__((address_space(1))) void*)g,
      (__attribute__((address_space(3))) void*)l, 16, 0, 0);
}

// ---------------- K0a: Q fp32 -> bf16 ----------------
__global__ __launch_bounds__(256) void k_cvt_q(const float* __restrict__ in,
                                               ushort_t* __restrict__ out) {
  int i = (blockIdx.x * 256 + threadIdx.x) * 4;
  float4 v = *(const float4*)(in + i);
  u16x4 o;
  o.x = f2bf(v.x); o.y = f2bf(v.y); o.z = f2bf(v.z); o.w = f2bf(v.w);
  *(u16x4*)(out + i) = o;
}

// ---------------- K0b: transpose + convert W [R][C] fp32 -> [C][R] bf16 ----
__global__ __launch_bounds__(256) void k_transpose_cvt(const float* __restrict__ in,
                                                       ushort_t* __restrict__ out,
                                                       int R, int C) {
  __shared__ float t[32][33];
  int bx = blockIdx.x, by = blockIdx.y;
  int tx = threadIdx.x & 31, ty = threadIdx.x >> 5;  // ty 0..7
#pragma unroll
  for (int i = 0; i < 4; ++i) {
    int r = by * 32 + ty + i * 8;
    t[ty + i * 8][tx] = in[(size_t)r * C + bx * 32 + tx];
  }
  __syncthreads();
#pragma unroll
  for (int i = 0; i < 4; ++i) {
    int orow = bx * 32 + ty + i * 8;  // output row = original col
    int ocol = by * 32 + tx;          // output col = original row
    out[(size_t)orow * R + ocol] = f2bf(t[tx][ty + i * 8]);
  }
}

// ---------------- K1: QKV GEMM (bf16 MFMA) + scatter epilogue -------------
__global__ __launch_bounds__(256) void k_gemm_qkv(
    const ushort_t* __restrict__ A,   // [4096][1024]
    const ushort_t* __restrict__ Bt,  // [3072][1024]
    const float* __restrict__ bias,   // [3072]
    ushort_t* __restrict__ qh,        // [B][H][S][64]
    ushort_t* __restrict__ kh,        // [B][H][S][64]
    ushort_t* __restrict__ vT) {      // [B][H][64][S]
  constexpr int K = 1024;
  __shared__ ushort_t lA[128 * 32];
  __shared__ ushort_t lB[128 * 32];
  const int t = threadIdx.x, lane = t & 63, w = t >> 6;
  const int wm = w >> 1, wn = w & 1;
  const int bm = blockIdx.x & 31, bn = blockIdx.x >> 5;  // 32 x 24

  f32x4 acc[4][4];
#pragma unroll
  for (int i = 0; i < 4; ++i)
#pragma unroll
    for (int j = 0; j < 4; ++j) acc[i][j] = f32x4{0.f, 0.f, 0.f, 0.f};

  const int srow = t >> 2;        // 0..63
  const int scol = (t & 3) * 8;   // 0,8,16,24
  for (int k0 = 0; k0 < K; k0 += 32) {
    __syncthreads();
    gll16(A + (size_t)(bm * 128 + srow) * K + k0 + scol, lA + srow * 32 + scol);
    gll16(A + (size_t)(bm * 128 + 64 + srow) * K + k0 + scol, lA + (64 + srow) * 32 + scol);
    gll16(Bt + (size_t)(bn * 128 + srow) * K + k0 + scol, lB + srow * 32 + scol);
    gll16(Bt + (size_t)(bn * 128 + 64 + srow) * K + k0 + scol, lB + (64 + srow) * 32 + scol);
    asm volatile("s_waitcnt vmcnt(0)" ::: "memory");
    __syncthreads();
    bf16x8 af[4], bfr[4];
#pragma unroll
    for (int i = 0; i < 4; ++i)
      af[i] = *(const bf16x8*)(lA + (wm * 64 + i * 16 + (lane & 15)) * 32 + (lane >> 4) * 8);
#pragma unroll
    for (int j = 0; j < 4; ++j)
      bfr[j] = *(const bf16x8*)(lB + (wn * 64 + j * 16 + (lane & 15)) * 32 + (lane >> 4) * 8);
#pragma unroll
    for (int i = 0; i < 4; ++i)
#pragma unroll
      for (int j = 0; j < 4; ++j)
        acc[i][j] = __builtin_amdgcn_mfma_f32_16x16x32_bf16(af[i], bfr[j], acc[i][j], 0, 0, 0);
  }
#pragma unroll
  for (int i = 0; i < 4; ++i) {
#pragma unroll
    for (int j = 0; j < 4; ++j) {
#pragma unroll
      for (int p = 0; p < 4; ++p) {
        int row = bm * 128 + wm * 64 + i * 16 + (lane >> 4) * 4 + p;  // token
        int col = bn * 128 + wn * 64 + j * 16 + (lane & 15);          // 0..3071
        float v = acc[i][j][p] + bias[col];
        ushort_t bv = f2bf(v);
        int b = row >> 11, s = row & (S_ - 1);
        int h = col / 192, r = col - h * 192;
        size_t bh = (size_t)(b * H_ + h);
        if (r < 64)
          qh[(bh * S_ + s) * 64 + r] = bv;
        else if (r < 128)
          kh[(bh * S_ + s) * 64 + (r - 64)] = bv;
        else
          vT[(bh * 64 + (r - 128)) * S_ + s] = bv;
      }
    }
  }
}

// ---------------- K2: scores = q@k^T * SCALE + prev -----------------------
__global__ __launch_bounds__(256) void k_scores(
    const ushort_t* __restrict__ qh, const ushort_t* __restrict__ kh,
    const float* __restrict__ prev, float* __restrict__ scores) {
  __shared__ ushort_t lQ[128 * 64];
  __shared__ ushort_t lK[128 * 64];
  const int t = threadIdx.x, lane = t & 63, w = t >> 6;
  const int wm = w >> 1, wn = w & 1;
  const int bn = blockIdx.x & 15, bm = (blockIdx.x >> 4) & 15, bh = blockIdx.x >> 8;
  const ushort_t* qb = qh + (size_t)bh * S_ * 64;
  const ushort_t* kb = kh + (size_t)bh * S_ * 64;
  const int srow = t >> 3;       // 0..31
  const int scol = (t & 7) * 8;  // 0..56
#pragma unroll
  for (int it = 0; it < 4; ++it) {
    gll16(qb + (size_t)(bm * 128 + it * 32 + srow) * 64 + scol, lQ + (it * 32 + srow) * 64 + scol);
    gll16(kb + (size_t)(bn * 128 + it * 32 + srow) * 64 + scol, lK + (it * 32 + srow) * 64 + scol);
  }
  asm volatile("s_waitcnt vmcnt(0)" ::: "memory");
  __syncthreads();

  f32x4 acc[4][4];
#pragma unroll
  for (int i = 0; i < 4; ++i)
#pragma unroll
    for (int j = 0; j < 4; ++j) acc[i][j] = f32x4{0.f, 0.f, 0.f, 0.f};

#pragma unroll
  for (int ks = 0; ks < 2; ++ks) {
    bf16x8 af[4], bfr[4];
#pragma unroll
    for (int i = 0; i < 4; ++i)
      af[i] = *(const bf16x8*)(lQ + (wm * 64 + i * 16 + (lane & 15)) * 64 + ks * 32 + (lane >> 4) * 8);
#pragma unroll
    for (int j = 0; j < 4; ++j)
      bfr[j] = *(const bf16x8*)(lK + (wn * 64 + j * 16 + (lane & 15)) * 64 + ks * 32 + (lane >> 4) * 8);
#pragma unroll
    for (int i = 0; i < 4; ++i)
#pragma unroll
      for (int j = 0; j < 4; ++j)
        acc[i][j] = __builtin_amdgcn_mfma_f32_16x16x32_bf16(af[i], bfr[j], acc[i][j], 0, 0, 0);
  }
  const size_t base = (size_t)bh * S_ * S_;
#pragma unroll
  for (int i = 0; i < 4; ++i) {
#pragma unroll
    for (int j = 0; j < 4; ++j) {
#pragma unroll
      for (int p = 0; p < 4; ++p) {
        int row = bm * 128 + wm * 64 + i * 16 + (lane >> 4) * 4 + p;
        int col = bn * 128 + wn * 64 + j * 16 + (lane & 15);
        size_t idx = base + (size_t)row * S_ + col;
        scores[idx] = acc[i][j][p] * 0.125f + prev[idx];
      }
    }
  }
}

// ---------------- K3: online softmax + PV (MFMA), per-wave 16 rows --------
__global__ __launch_bounds__(256) void k_attn_pv(
    const float* __restrict__ scores, const ushort_t* __restrict__ vT,
    ushort_t* __restrict__ ctx) {
  const int t = threadIdx.x, lane = t & 63, w = t >> 6;
  const int rowTile = blockIdx.x & 31, bh = blockIdx.x >> 5;
  const int row0 = rowTile * 64 + w * 16;
  const float* sc = scores + (size_t)bh * S_ * S_ + (size_t)(row0 + (lane & 15)) * S_;
  const ushort_t* vb = vT + (size_t)bh * 64 * S_;
  const int klo = (lane >> 4) * 8;

  f32x4 acc[4];
#pragma unroll
  for (int dn = 0; dn < 4; ++dn) acc[dn] = f32x4{0.f, 0.f, 0.f, 0.f};
  float m_run = -1e30f, l_run = 0.f;

  for (int kt = 0; kt < S_; kt += 128) {
    float p[4][8];
#pragma unroll
    for (int ks = 0; ks < 4; ++ks) {
      const float* src = sc + kt + ks * 32 + klo;
      float4 v0 = *(const float4*)(src);
      float4 v1 = *(const float4*)(src + 4);
      p[ks][0] = v0.x; p[ks][1] = v0.y; p[ks][2] = v0.z; p[ks][3] = v0.w;
      p[ks][4] = v1.x; p[ks][5] = v1.y; p[ks][6] = v1.z; p[ks][7] = v1.w;
    }
    float tmax = -1e30f;
#pragma unroll
    for (int ks = 0; ks < 4; ++ks)
#pragma unroll
      for (int j = 0; j < 8; ++j) tmax = fmaxf(tmax, p[ks][j]);
    tmax = fmaxf(tmax, __shfl_xor(tmax, 16));
    tmax = fmaxf(tmax, __shfl_xor(tmax, 32));
    float m_new = fmaxf(m_run, tmax);
    float f = __expf(m_run - m_new);
    m_run = m_new;

    float lsum = 0.f;
    bf16x8 pa[4];
#pragma unroll
    for (int ks = 0; ks < 4; ++ks) {
      bf16x8 pv;
#pragma unroll
      for (int j = 0; j < 8; ++j) {
        float e = __expf(p[ks][j] - m_new);
        lsum += e;
        pv[j] = (short)f2bf(e);
      }
      pa[ks] = pv;
    }
    lsum += __shfl_xor(lsum, 16);
    lsum += __shfl_xor(lsum, 32);
    l_run = l_run * f + lsum;

    float fr[4];
#pragma unroll
    for (int pp = 0; pp < 4; ++pp) fr[pp] = __shfl(f, ((lane >> 4) << 2) + pp);
#pragma unroll
    for (int dn = 0; dn < 4; ++dn)
#pragma unroll
      for (int pp = 0; pp < 4; ++pp) acc[dn][pp] *= fr[pp];

#pragma unroll
    for (int ks = 0; ks < 4; ++ks) {
#pragma unroll
      for (int dn = 0; dn < 4; ++dn) {
        bf16x8 vf = *(const bf16x8*)(vb + (size_t)(dn * 16 + (lane & 15)) * S_ + kt + ks * 32 + klo);
        acc[dn] = __builtin_amdgcn_mfma_f32_16x16x32_bf16(pa[ks], vf, acc[dn], 0, 0, 0);
      }
    }
  }

  float inv[4];
#pragma unroll
  for (int pp = 0; pp < 4; ++pp) inv[pp] = 1.0f / __shfl(l_run, ((lane >> 4) << 2) + pp);
  const int b = bh >> 4, h = bh & 15;
#pragma unroll
  for (int dn = 0; dn < 4; ++dn) {
#pragma unroll
    for (int pp = 0; pp < 4; ++pp) {
      int srowg = row0 + (lane >> 4) * 4 + pp;
      int token = b * S_ + srowg;
      ctx[(size_t)token * D_ + h * 64 + dn * 16 + (lane & 15)] = f2bf(acc[dn][pp] * inv[pp]);
    }
  }
}

// ---------------- K4: output GEMM + bias (fp32 out) -----------------------
__global__ __launch_bounds__(256) void k_gemm_out(
    const ushort_t* __restrict__ A,   // ctx [4096][1024]
    const ushort_t* __restrict__ Bt,  // WoutT [1024][1024]
    const float* __restrict__ bias,   // [1024]
    float* __restrict__ out) {
  constexpr int K = 1024;
  __shared__ ushort_t lA[128 * 32];
  __shared__ ushort_t lB[128 * 32];
  const int t = threadIdx.x, lane = t & 63, w = t >> 6;
  const int wm = w >> 1, wn = w & 1;
  const int bm = blockIdx.x & 31, bn = blockIdx.x >> 5;  // 32 x 8

  f32x4 acc[4][4];
#pragma unroll
  for (int i = 0; i < 4; ++i)
#pragma unroll
    for (int j = 0; j < 4; ++j) acc[i][j] = f32x4{0.f, 0.f, 0.f, 0.f};

  const int srow = t >> 2;
  const int scol = (t & 3) * 8;
  for (int k0 = 0; k0 < K; k0 += 32) {
    __syncthreads();
    gll16(A + (size_t)(bm * 128 + srow) * K + k0 + scol, lA + srow * 32 + scol);
    gll16(A + (size_t)(bm * 128 + 64 + srow) * K + k0 + scol, lA + (64 + srow) * 32 + scol);
    gll16(Bt + (size_t)(bn * 128 + srow) * K + k0 + scol, lB + srow * 32 + scol);
    gll16(Bt + (size_t)(bn * 128 + 64 + srow) * K + k0 + scol, lB + (64 + srow) * 32 + scol);
    asm volatile("s_waitcnt vmcnt(0)" ::: "memory");
    __syncthreads();
    bf16x8 af[4], bfr[4];
#pragma unroll
    for (int i = 0; i < 4; ++i)
      af[i] = *(const bf16x8*)(lA + (wm * 64 + i * 16 + (lane & 15)) * 32 + (lane >> 4) * 8);
#pragma unroll
    for (int j = 0; j < 4; ++j)
      bfr[j] = *(const bf16x8*)(lB + (wn * 64 + j * 16 + (lane & 15)) * 32 + (lane >> 4) * 8);
#pragma unroll
    for (int i = 0; i < 4; ++i)
#pragma unroll
      for (int j = 0; j < 4; ++j)
        acc[i][j] = __builtin_amdgcn_mfma_f32_16x16x32_bf16(af[i], bfr[j], acc[i][j], 0, 0, 0);
  }
#pragma unroll
  for (int i = 0; i < 4; ++i) {
#pragma unroll
    for (int j = 0; j < 4; ++j) {
#pragma unroll
      for (int p = 0; p < 4; ++p) {
        int row = bm * 128 + wm * 64 + i * 16 + (lane >> 4) * 4 + p;
        int col = bn * 128 + wn * 64 + j * 16 + (lane & 15);
        out[(size_t)row * 1024 + col] = acc[i][j][p] + bias[col];
      }
    }
  }
}

extern "C" void kernel_launch(void* const* d_in, const int* in_sizes, int n_in,
                              void* d_out, int out_size, void* d_ws, size_t ws_size,
                              hipStream_t stream) {
  (void)in_sizes; (void)n_in; (void)out_size; (void)ws_size;
  const float* Q     = (const float*)d_in[0];
  const float* prev  = (const float*)d_in[1];
  const float* W_qkv = (const float*)d_in[2];
  const float* b_qkv = (const float*)d_in[3];
  const float* W_out = (const float*)d_in[4];
  const float* b_out = (const float*)d_in[5];
  float* out = (float*)d_out;
  float* scores_out = out + (size_t)M_TOK * D_;  // output first, then scores

  char* ws = (char*)d_ws;
  ushort_t* Qb    = (ushort_t*)(ws + (size_t)0);          // 8 MB
  ushort_t* WqkvT = (ushort_t*)(ws + ((size_t)8  << 20)); // 6 MB
  ushort_t* WoutT = (ushort_t*)(ws + ((size_t)14 << 20)); // 2 MB
  ushort_t* qh    = (ushort_t*)(ws + ((size_t)16 << 20)); // 8 MB
  ushort_t* kh    = (ushort_t*)(ws + ((size_t)24 << 20)); // 8 MB
  ushort_t* vT    = (ushort_t*)(ws + ((size_t)32 << 20)); // 8 MB
  ushort_t* ctx   = (ushort_t*)(ws + ((size_t)40 << 20)); // 8 MB  => 48 MB total

  k_cvt_q<<<4096, 256, 0, stream>>>(Q, Qb);
  k_transpose_cvt<<<dim3(96, 32), 256, 0, stream>>>(W_qkv, WqkvT, 1024, 3072);
  k_transpose_cvt<<<dim3(32, 32), 256, 0, stream>>>(W_out, WoutT, 1024, 1024);
  k_gemm_qkv<<<768, 256, 0, stream>>>(Qb, WqkvT, b_qkv, qh, kh, vT);
  k_scores<<<8192, 256, 0, stream>>>(qh, kh, prev, scores_out);
  k_attn_pv<<<1024, 256, 0, stream>>>(scores_out, vT, ctx);
  k_gemm_out<<<256, 256, 0, stream>>>(ctx, WoutT, b_out, out);
}